// Round 1
// baseline (717.523 us; speedup 1.0000x reference)
//
#include <hip/hip_runtime.h>
#include <hip/hip_bf16.h>
#include <stdint.h>
#include <math.h>

// Problem constants (reference: DIM=512, B=16, L=2048, MLP_RATIO=4, GATE_HID=128)
#define DIMC 512
#define SEQ  2048
#define NB   16
#define MTOT (NB * SEQ)          // 32768 tokens
#define HID  2048

typedef short short8 __attribute__((ext_vector_type(8)));
typedef float v4f    __attribute__((ext_vector_type(4)));

__device__ __forceinline__ float bf2f(unsigned short u) {
  union { unsigned int i; float f; } v; v.i = ((unsigned int)u) << 16; return v.f;
}
__device__ __forceinline__ unsigned short f2bf(float f) {
  union { float f; unsigned int i; } v; v.f = f;
  unsigned int r = v.i + 0x7fffu + ((v.i >> 16) & 1u);  // RNE
  return (unsigned short)(r >> 16);
}
__device__ __forceinline__ float gelu_f(float v) {
  return 0.5f * v * (1.f + erff(v * 0.70710678118654752440f));
}

typedef __attribute__((address_space(1))) const void cglobal_void;
typedef __attribute__((address_space(3))) void lds_void;
__device__ __forceinline__ void load16_lds(const void* g, void* l) {
  // async 16B/lane global->LDS; LDS dest = wave-uniform base + lane*16
  __builtin_amdgcn_global_load_lds((cglobal_void*)g, (lds_void*)l, 16, 0, 0);
}

// ---------------------------------------------------------------------------
// Weight pack: fp32 -> bf16, optional transpose. out[r*C+c] = in[c*R+r] if trans.
// ---------------------------------------------------------------------------
__global__ __launch_bounds__(256) void pack_w(const float* __restrict__ in,
                                              unsigned short* __restrict__ out,
                                              int R, int C, int trans) {
  int i = blockIdx.x * 256 + threadIdx.x;
  if (i >= R * C) return;
  int r = i / C, c = i - r * C;
  float v = trans ? in[(size_t)c * R + r] : in[i];
  out[i] = f2bf(v);
}

// ---------------------------------------------------------------------------
// Kernel A: LN1 + (dwconv3+dwconv5+dwconv7)/3 + GELU -> g bf16 [M, 512]
// Also accumulates gsum[b][d] = sum_l g (for the gate path, by linearity).
// One block = 32 tokens of one batch; LDS tile has 3-token halo each side.
// ---------------------------------------------------------------------------
__global__ __launch_bounds__(256) void ln1_conv(
    const float* __restrict__ x, const float* __restrict__ lg, const float* __restrict__ lb,
    const float* __restrict__ w3, const float* __restrict__ b3,
    const float* __restrict__ w5, const float* __restrict__ b5,
    const float* __restrict__ w7, const float* __restrict__ b7,
    unsigned short* __restrict__ gout, float* __restrict__ gsum) {
  __shared__ __align__(16) unsigned short ht[38 * DIMC];  // bf16 normalized tile
  int blk = blockIdx.x;
  int b = blk >> 6;
  int l0 = (blk & 63) << 5;   // 32-token chunk
  int tid = threadIdx.x, lane = tid & 63, w = tid >> 6;

  // LN phase: wave per token row (rows 0..37 = tokens l0-3 .. l0+34)
  for (int r = w; r < 38; r += 4) {
    int l = l0 - 3 + r;
    unsigned short* hrow = ht + r * DIMC;
    if (l < 0 || l >= SEQ) {
      ushort4 z; z.x = z.y = z.z = z.w = 0;
      *(ushort4*)&hrow[lane * 4] = z;
      *(ushort4*)&hrow[256 + lane * 4] = z;
    } else {
      const float4* xp = (const float4*)(x + ((size_t)(b * SEQ + l)) * DIMC);
      float4 v0 = xp[lane], v1 = xp[lane + 64];
      float s = v0.x + v0.y + v0.z + v0.w + v1.x + v1.y + v1.z + v1.w;
      float q = v0.x * v0.x + v0.y * v0.y + v0.z * v0.z + v0.w * v0.w +
                v1.x * v1.x + v1.y * v1.y + v1.z * v1.z + v1.w * v1.w;
#pragma unroll
      for (int o = 32; o > 0; o >>= 1) { s += __shfl_xor(s, o); q += __shfl_xor(q, o); }
      float mu = s * (1.f / 512.f);
      float rs = rsqrtf(q * (1.f / 512.f) - mu * mu + 1e-5f);
      float4 ga = ((const float4*)lg)[lane], gb = ((const float4*)lg)[lane + 64];
      float4 ba = ((const float4*)lb)[lane], bb = ((const float4*)lb)[lane + 64];
      ushort4 o0, o1;
      o0.x = f2bf((v0.x - mu) * rs * ga.x + ba.x);
      o0.y = f2bf((v0.y - mu) * rs * ga.y + ba.y);
      o0.z = f2bf((v0.z - mu) * rs * ga.z + ba.z);
      o0.w = f2bf((v0.w - mu) * rs * ga.w + ba.w);
      o1.x = f2bf((v1.x - mu) * rs * gb.x + bb.x);
      o1.y = f2bf((v1.y - mu) * rs * gb.y + bb.y);
      o1.z = f2bf((v1.z - mu) * rs * gb.z + bb.z);
      o1.w = f2bf((v1.w - mu) * rs * gb.w + bb.w);
      *(ushort4*)&hrow[lane * 4] = o0;
      *(ushort4*)&hrow[256 + lane * 4] = o1;
    }
  }
  __syncthreads();

  // Conv phase: thread handles channel pair d0, d0+1 across 32 tokens.
  int d0 = tid << 1;
  float t3[2][3], t5[2][5], t7[2][7], cb[2];
#pragma unroll
  for (int j = 0; j < 2; j++) {
    int d = d0 + j;
    cb[j] = b3[d] + b5[d] + b7[d];
#pragma unroll
    for (int t = 0; t < 3; t++) t3[j][t] = w3[d * 3 + t];
#pragma unroll
    for (int t = 0; t < 5; t++) t5[j][t] = w5[d * 5 + t];
#pragma unroll
    for (int t = 0; t < 7; t++) t7[j][t] = w7[d * 7 + t];
  }
  float sum0 = 0.f, sum1 = 0.f;
  size_t obase = ((size_t)(b * SEQ + l0)) * DIMC + d0;
  for (int l = 0; l < 32; l++) {
    float h0[7], h1[7];
#pragma unroll
    for (int r = 0; r < 7; r++) {
      unsigned int pk = *(const unsigned int*)&ht[(l + r) * DIMC + d0];
      h0[r] = bf2f((unsigned short)pk);
      h1[r] = bf2f((unsigned short)(pk >> 16));
    }
    float a0 = cb[0], a1 = cb[1];
#pragma unroll
    for (int t = 0; t < 7; t++) { a0 += t7[0][t] * h0[t];     a1 += t7[1][t] * h1[t]; }
#pragma unroll
    for (int t = 0; t < 5; t++) { a0 += t5[0][t] * h0[t + 1]; a1 += t5[1][t] * h1[t + 1]; }
#pragma unroll
    for (int t = 0; t < 3; t++) { a0 += t3[0][t] * h0[t + 2]; a1 += t3[1][t] * h1[t + 2]; }
    a0 *= (1.f / 3.f); a1 *= (1.f / 3.f);
    float g0 = gelu_f(a0), g1 = gelu_f(a1);
    unsigned int opk = (unsigned int)f2bf(g0) | ((unsigned int)f2bf(g1) << 16);
    *(unsigned int*)((unsigned short*)gout + obase + (size_t)l * DIMC) = opk;
    sum0 += g0; sum1 += g1;
  }
  atomicAdd(&gsum[b * DIMC + d0], sum0);
  atomicAdd(&gsum[b * DIMC + d0 + 1], sum1);
}

// ---------------------------------------------------------------------------
// Gate: ct = (gsum/L) @ wmix^T + bmix ; gate = sigmoid(gelu(ct@cg_w1+b1)@cg_w2+b2)
// One block per batch element. Tiny (fp32, exact path has 1e-4 damping anyway).
// ---------------------------------------------------------------------------
__global__ __launch_bounds__(128) void gate_kernel(
    const float* __restrict__ gsum, const float* __restrict__ wmix, const float* __restrict__ bmix,
    const float* __restrict__ cg_w1, const float* __restrict__ cg_b1,
    const float* __restrict__ cg_w2, const float* __restrict__ cg_b2,
    float* __restrict__ gate) {
  __shared__ float gbar[512], ct[512], t1[128];
  int b = blockIdx.x, tid = threadIdx.x;
  for (int i = tid; i < 512; i += 128) gbar[i] = gsum[b * 512 + i] * (1.f / (float)SEQ);
  __syncthreads();
  for (int o = tid; o < 512; o += 128) {
    float s = bmix[o];
    const float* wr = wmix + (size_t)o * 512;
    for (int c = 0; c < 512; c++) s += gbar[c] * wr[c];
    ct[o] = s;
  }
  __syncthreads();
  {
    float s = cg_b1[tid];
    for (int c = 0; c < 512; c++) s += ct[c] * cg_w1[c * 128 + tid];
    t1[tid] = gelu_f(s);
  }
  __syncthreads();
  for (int o = tid; o < 512; o += 128) {
    float s = cg_b2[o];
    for (int h = 0; h < 128; h++) s += t1[h] * cg_w2[h * 512 + o];
    gate[b * 512 + o] = 1.f / (1.f + expf(-s));
  }
}

// ---------------------------------------------------------------------------
// LN2: h2 = LN(y) in bf16. One wave per token.
// ---------------------------------------------------------------------------
__global__ __launch_bounds__(256) void ln2_kernel(
    const float* __restrict__ y, const float* __restrict__ lg, const float* __restrict__ lb,
    unsigned short* __restrict__ h2) {
  int tok = (blockIdx.x << 2) + (threadIdx.x >> 6);
  int lane = threadIdx.x & 63;
  const float4* yp = (const float4*)(y + ((size_t)tok) * DIMC);
  float4 v0 = yp[lane], v1 = yp[lane + 64];
  float s = v0.x + v0.y + v0.z + v0.w + v1.x + v1.y + v1.z + v1.w;
  float q = v0.x * v0.x + v0.y * v0.y + v0.z * v0.z + v0.w * v0.w +
            v1.x * v1.x + v1.y * v1.y + v1.z * v1.z + v1.w * v1.w;
#pragma unroll
  for (int o = 32; o > 0; o >>= 1) { s += __shfl_xor(s, o); q += __shfl_xor(q, o); }
  float mu = s * (1.f / 512.f);
  float rs = rsqrtf(q * (1.f / 512.f) - mu * mu + 1e-5f);
  float4 ga = ((const float4*)lg)[lane], gb = ((const float4*)lg)[lane + 64];
  float4 ba = ((const float4*)lb)[lane], bb = ((const float4*)lb)[lane + 64];
  ushort4 o0, o1;
  o0.x = f2bf((v0.x - mu) * rs * ga.x + ba.x);
  o0.y = f2bf((v0.y - mu) * rs * ga.y + ba.y);
  o0.z = f2bf((v0.z - mu) * rs * ga.z + ba.z);
  o0.w = f2bf((v0.w - mu) * rs * ga.w + ba.w);
  o1.x = f2bf((v1.x - mu) * rs * gb.x + bb.x);
  o1.y = f2bf((v1.y - mu) * rs * gb.y + bb.y);
  o1.z = f2bf((v1.z - mu) * rs * gb.z + bb.z);
  o1.w = f2bf((v1.w - mu) * rs * gb.w + bb.w);
  unsigned short* hp = h2 + (size_t)tok * DIMC;
  *(ushort4*)&hp[lane * 4] = o0;
  *(ushort4*)&hp[256 + lane * 4] = o1;
}

// ---------------------------------------------------------------------------
// bf16 GEMM, C = A @ B^T (+epilogue). A [M,K] row-major, B [N,K] row-major.
// 128x128 tile, BK=64, 4 waves of 4x4 mfma_f32_16x16x32_bf16 fragments,
// global_load_lds(16B) staging (m97 recipe).
// MODE 1: out bf16 = (acc + bias[col]) * gate[(m0>>11)*512 + col]
// MODE 2: out f32  = resid[idx] + (acc + bias[col]) * scale[col]
// MODE 3: out bf16 = gelu(acc + bias[col])
// MODE 4: out f32 += (acc + (bias?bias[col]:0)) * scale[col]   (RMW accumulate)
// ---------------------------------------------------------------------------
template <int MODE>
__global__ __launch_bounds__(256) void gemm_bt(
    const short* __restrict__ A, const short* __restrict__ B, int ldb,
    const float* __restrict__ bias, const float* __restrict__ scale,
    const float* __restrict__ resid, void* __restrict__ outp,
    int N, int K, const float* __restrict__ gate) {
  __shared__ __align__(16) short As[128 * 64];
  __shared__ __align__(16) short Bs[128 * 64];
  const int m0 = blockIdx.x * 128, n0 = blockIdx.y * 128;
  const int tid = threadIdx.x, lane = tid & 63, w = tid >> 6;
  const int wm = w >> 1, wn = w & 1, quad = lane >> 4, cn = lane & 15;
  const int lr = lane >> 3, lc = lane & 7;

  v4f acc[4][4];
  v4f zero4 = {0.f, 0.f, 0.f, 0.f};
#pragma unroll
  for (int i = 0; i < 4; i++)
#pragma unroll
    for (int j = 0; j < 4; j++) acc[i][j] = zero4;

  for (int k0 = 0; k0 < K; k0 += 64) {
    __syncthreads();  // previous LDS consumers done
#pragma unroll
    for (int s = 0; s < 4; s++) {
      int seg = (w << 2) + s;           // 16 segments of 8 rows x 64 cols
      int row = (seg << 3) + lr;
      load16_lds(A + (size_t)(m0 + row) * K + k0 + (lc << 3), &As[seg * 512]);
      load16_lds(B + (size_t)(n0 + row) * ldb + k0 + (lc << 3), &Bs[seg * 512]);
    }
    __syncthreads();  // staging visible (compiler drains vmcnt before barrier)
#pragma unroll
    for (int kk = 0; kk < 2; kk++) {
      short8 af[4], bf[4];
#pragma unroll
      for (int mt = 0; mt < 4; mt++)
        af[mt] = *(const short8*)&As[(wm * 64 + mt * 16 + cn) * 64 + kk * 32 + quad * 8];
#pragma unroll
      for (int nt = 0; nt < 4; nt++)
        bf[nt] = *(const short8*)&Bs[(wn * 64 + nt * 16 + cn) * 64 + kk * 32 + quad * 8];
#pragma unroll
      for (int mt = 0; mt < 4; mt++)
#pragma unroll
        for (int nt = 0; nt < 4; nt++)
          acc[mt][nt] = __builtin_amdgcn_mfma_f32_16x16x32_bf16(af[mt], bf[nt], acc[mt][nt], 0, 0, 0);
    }
  }

  // Epilogue. C/D layout: col = lane&15, row = quad*4 + reg (m89/m91-verified).
  const int bb = (MODE == 1) ? (m0 >> 11) : 0;
#pragma unroll
  for (int mt = 0; mt < 4; mt++) {
    int row = m0 + wm * 64 + mt * 16 + quad * 4;
#pragma unroll
    for (int nt = 0; nt < 4; nt++) {
      int col = n0 + wn * 64 + nt * 16 + cn;
      float bv = (MODE == 4) ? (bias ? bias[col] : 0.f) : bias[col];
      float sv = (MODE == 2 || MODE == 4) ? scale[col] : 0.f;
      float gv = (MODE == 1) ? gate[bb * 512 + col] : 0.f;
#pragma unroll
      for (int r = 0; r < 4; r++) {
        size_t idx = (size_t)(row + r) * N + col;
        float v = acc[mt][nt][r];
        if (MODE == 1) {
          ((unsigned short*)outp)[idx] = f2bf((v + bv) * gv);
        } else if (MODE == 2) {
          ((float*)outp)[idx] = resid[idx] + (v + bv) * sv;
        } else if (MODE == 3) {
          ((unsigned short*)outp)[idx] = f2bf(gelu_f(v + bv));
        } else {
          float* op = (float*)outp;
          op[idx] = op[idx] + (v + bv) * sv;
        }
      }
    }
  }
}

// ---------------------------------------------------------------------------
extern "C" void kernel_launch(void* const* d_in, const int* in_sizes, int n_in,
                              void* d_out, int out_size, void* d_ws, size_t ws_size,
                              hipStream_t stream) {
  (void)in_sizes; (void)n_in; (void)out_size;
  const float* x     = (const float*)d_in[0];
  const float* ln1_g = (const float*)d_in[1];
  const float* ln1_b = (const float*)d_in[2];
  const float* w3    = (const float*)d_in[3];
  const float* b3    = (const float*)d_in[4];
  const float* w5    = (const float*)d_in[5];
  const float* b5    = (const float*)d_in[6];
  const float* w7    = (const float*)d_in[7];
  const float* b7    = (const float*)d_in[8];
  const float* wmix  = (const float*)d_in[9];
  const float* bmix  = (const float*)d_in[10];
  const float* cg_w1 = (const float*)d_in[11];
  const float* cg_b1 = (const float*)d_in[12];
  const float* cg_w2 = (const float*)d_in[13];
  const float* cg_b2 = (const float*)d_in[14];
  const float* wout  = (const float*)d_in[15];
  const float* bout  = (const float*)d_in[16];
  const float* ls1   = (const float*)d_in[17];
  const float* ln2_g = (const float*)d_in[18];
  const float* ln2_b = (const float*)d_in[19];
  const float* ffn_w1= (const float*)d_in[20];
  const float* ffn_b1= (const float*)d_in[21];
  const float* ffn_w2= (const float*)d_in[22];
  const float* ffn_b2= (const float*)d_in[23];
  const float* ls2   = (const float*)d_in[24];

  char* ws = (char*)d_ws;
  // workspace layout (bytes)
  unsigned short* wmix_b = (unsigned short*)(ws + 0);          // 512KB
  unsigned short* woutT  = (unsigned short*)(ws + 524288);     // 512KB
  unsigned short* w1T    = (unsigned short*)(ws + 1048576);    // 2MB  [2048][512]
  unsigned short* w2T    = (unsigned short*)(ws + 3145728);    // 2MB  [512][2048]
  float*          gsum   = (float*)(ws + 5242880);             // 32KB
  float*          gate   = (float*)(ws + 5275648);             // 32KB
  unsigned short* gbuf   = (unsigned short*)(ws + 6291456);    // 32MB  (g, then reused as h2)
  unsigned short* h2buf  = gbuf;                               // overlap: g dead after GEMM1
  unsigned short* attn   = (unsigned short*)(ws + 39845888);   // 32MB  (then reused as FFN t-buffer)
  unsigned short* tbuf   = attn;                               // overlap: attn dead after GEMM2

  // FFN hidden chunk size chosen from available workspace (constant per run).
  int HC;
  if (ws_size >= (size_t)39845888 + 67108864)      HC = 1024;  // t-buf 64MB
  else if (ws_size >= (size_t)39845888 + 33554432) HC = 512;   // t-buf 32MB
  else                                             HC = 256;   // t-buf 16MB

  hipMemsetAsync(gsum, 0, NB * DIMC * sizeof(float), stream);

  // weight packing (bf16, B-operand layout [N][K])
  pack_w<<<(512 * 512 + 255) / 256, 256, 0, stream>>>(wmix,   wmix_b, 512, 512, 0);
  pack_w<<<(512 * 512 + 255) / 256, 256, 0, stream>>>(wout,   woutT,  512, 512, 1);
  pack_w<<<(2048 * 512 + 255) / 256, 256, 0, stream>>>(ffn_w1, w1T,  2048, 512, 1);
  pack_w<<<(2048 * 512 + 255) / 256, 256, 0, stream>>>(ffn_w2, w2T,   512, 2048, 1);

  // LN1 + dwconv + gelu + gbar partials
  ln1_conv<<<NB * 64, 256, 0, stream>>>(x, ln1_g, ln1_b, w3, b3, w5, b5, w7, b7, gbuf, gsum);

  // gate [16,512]
  gate_kernel<<<NB, 128, 0, stream>>>(gsum, wmix, bmix, cg_w1, cg_b1, cg_w2, cg_b2, gate);

  dim3 grid_d(MTOT / 128, DIMC / 128);  // (256, 4)
  // GEMM1: attn = (g @ wmix^T + bmix) * gate   -> bf16
  gemm_bt<1><<<grid_d, 256, 0, stream>>>((const short*)gbuf, (const short*)wmix_b, 512,
                                         bmix, nullptr, nullptr, attn, 512, 512, gate);
  // GEMM2: y1 = x + (attn @ wout + bout) * ls1 -> d_out fp32
  gemm_bt<2><<<grid_d, 256, 0, stream>>>((const short*)attn, (const short*)woutT, 512,
                                         bout, ls1, x, d_out, 512, 512, nullptr);
  // LN2
  ln2_kernel<<<MTOT / 4, 256, 0, stream>>>((const float*)d_out, ln2_g, ln2_b, h2buf);

  // FFN, chunked over hidden dim; GEMM4 accumulates into d_out (RMW)
  int nch = HID / HC;
  for (int c = 0; c < nch; c++) {
    dim3 g3(MTOT / 128, HC / 128);
    gemm_bt<3><<<g3, 256, 0, stream>>>((const short*)h2buf,
                                       (const short*)(w1T + (size_t)c * HC * 512), 512,
                                       ffn_b1 + c * HC, nullptr, nullptr, tbuf, HC, 512, nullptr);
    gemm_bt<4><<<grid_d, 256, 0, stream>>>((const short*)tbuf,
                                           (const short*)(w2T + c * HC), 2048,
                                           (c == 0) ? ffn_b2 : nullptr, ls2, nullptr,
                                           d_out, 512, HC, nullptr);
  }
}